// Round 6
// baseline (375.073 us; speedup 1.0000x reference)
//
#include <hip/hip_runtime.h>
#include <hip/hip_bf16.h>

typedef unsigned short u16;
typedef unsigned int   u32;

#define KPS     39
#define DIN     78
#define DHID    195
#define NTOKTOT (256*2048)

#define M1T     13      // 13 x 16 = 208 rows (DHID padded)
#define K1S     3       // 3 x 32 = 96  (joined 78 + bias slot, padded)
#define M2T     5       // 5 x 16 = 80 rows (DIN padded)
#define K2S     7       // 7 x 32 = 224 (DHID + bias col padded)
#define NW      12      // 12 waves -> 3 waves/EU, 168-reg budget
#define NTHR    (NW*64) // 768
#define TPI     (NW*16) // 192 tokens per full block-iteration
#define TPB     2048
#define FIT     10      // 10 full iters + 1 partial (128 tokens, waves 0-7)
#define NBLK    (NTOKTOT/TPB)   // 256 blocks = 1 per CU

// packed MFMA-fragment weight layouts: slot = (m*K + kt)*64 + lane, 16B each
#define W1F_E (M1T*K1S*64*8)    // 19968 u16 = 39936 B
#define W2F_E (M2T*K2S*64*8)    // 17920 u16 = 35840 B
#define XYB_F (NW*1248)         // per-wave [624 x][624 y] f32 = 4992 B; total 59904 B
// + AB2 624 + B2C 312  -> total 136616 <= 163840
#define SMEM_BYTES ((W1F_E+W2F_E)*2 + XYB_F*4 + DIN*2*4 + DIN*4)

typedef __attribute__((ext_vector_type(8))) short short8;
typedef __attribute__((ext_vector_type(4))) float float4v;
typedef __attribute__((ext_vector_type(4))) u32   uint4v;

static __device__ __forceinline__ u16 f2b(float v) {
  __hip_bfloat16 b = __float2bfloat16(v);
  return __builtin_bit_cast(u16, b);
}

// async global->LDS, 16B per lane; dest = uniform base + lane*16
static __device__ __forceinline__ void glds16(const float* g, float* l) {
  __builtin_amdgcn_global_load_lds((const __attribute__((address_space(1))) void*)g,
                                   (__attribute__((address_space(3))) void*)l,
                                   16, 0, 0);
}

extern "C" __global__
__attribute__((amdgpu_flat_work_group_size(NTHR, NTHR), amdgpu_waves_per_eu(3, 3)))
void fused_mlp_kernel(const float* __restrict__ xp,  const float* __restrict__ yp,
                      const float* __restrict__ W1p, const float* __restrict__ b1p,
                      const float* __restrict__ W2p, const float* __restrict__ b2p,
                      const float* __restrict__ a1p, const float* __restrict__ a2p,
                      const float* __restrict__ al1p,const float* __restrict__ be1p,
                      const float* __restrict__ al2p,const float* __restrict__ be2p,
                      float* __restrict__ out0, float* __restrict__ out1)
{
  extern __shared__ char smem[];
  u16*   W1F = (u16*)smem;            // packed A-frags of W1, col-permuted (see below)
  u16*   W2F = W1F + W1F_E;           // packed A-frags of W2*alpha1, K-permuted
  float* XYB = (float*)(W2F + W2F_E); // per-wave f32 staging: [624 x][624 y]
  float* AB2 = XYB + XYB_F;           // interleaved alpha2/beta2
  float* B2C = AB2 + DIN*2;           // bias2 = b2 + W2*beta1

  const int tid  = threadIdx.x;
  const int lane = tid & 63;
  const int w    = tid >> 6;
  const int c    = lane & 15;   // A m-index / B n-index / C-D col (verified mapping)
  const int quad = lane >> 4;   // A/B k-block = quad*8 ; C/D row = quad*4+reg
  const int wr   = w * 16;
  const int blockTok = blockIdx.x * TPB;

  // ---------------- one-time per-block staging ----------------
  // bias2 partial sums (4 threads per output d), scratch in (future) XYB region
  {
    float* SCR = XYB;
    if (tid < DIN*4) {
      int d = tid >> 2, p = tid & 3;
      float s = (p == 0) ? b2p[d] : 0.f;
      const float* wrow = W2p + d*DHID;
      for (int j = p; j < DHID; j += 4) s = __builtin_fmaf(wrow[j], be1p[j], s);
      SCR[tid] = s;
    }
  }
  __syncthreads();
  if (tid < DIN) {
    const float* SCR = XYB;
    float bsum = SCR[4*tid] + SCR[4*tid+1] + SCR[4*tid+2] + SCR[4*tid+3];
    B2C[tid] = bsum;
    AB2[2*tid+0] = al2p[tid];
    AB2[2*tid+1] = be2p[tid];
  }
  __syncthreads();
  // W1 fragments, columns permuted to match the f32 LDS staging layout:
  //  kt0:        (qq,e) <-> k = qq*8+e              (x cols 0..31)
  //  kt1: qq0:   e<7 -> k=32+e (x 32..38), e7 dead
  //       qq1-3: k = 39+(qq-1)*8+e                  (y cols 0..23)
  //  kt2: qq0:   k = 63+e                           (y 24..31)
  //       qq1:   e<7 -> k=71+e (y 32..38), e7 dead
  //       qq2:   e0 -> b1[row] (B supplies 1.0), rest dead
  //       qq3:   dead
  for (int s = tid; s < M1T*K1S*64; s += NTHR) {
    int m = s/(K1S*64), r = s - m*(K1S*64);
    int kt = r >> 6, l = r & 63;
    int cc = l & 15, qq = l >> 4;
    int row = m*16 + cc;
    short8 v;
    #pragma unroll
    for (int e = 0; e < 8; ++e) {
      float f = 0.f;
      if (row < DHID) {
        int k = -1;
        if (kt == 0)      k = qq*8 + e;
        else if (kt == 1) k = (qq == 0) ? ((e < 7) ? 32 + e : -1)
                                        : 39 + (qq-1)*8 + e;
        else {            // kt == 2
          if (qq == 0)      k = 63 + e;
          else if (qq == 1) k = (e < 7) ? 71 + e : -1;
          else if (qq == 2 && e == 0) f = b1p[row];
        }
        if (k >= 0) f = W1p[row*DIN + k];
      }
      v[e] = (short)f2b(f);
    }
    *(short8*)&W1F[(size_t)s*8] = v;
  }
  // W2 fragments (alpha1 folded; bias col at logical k=DHID from B2C).
  // K-PERMUTED so GEMM2's B-fragment is each lane's own post-LN1 registers:
  //   position (qq,e) in tile kt  <->  logical k = kt*32 + (e>>2)*16 + qq*4 + (e&3)
  for (int s = tid; s < M2T*K2S*64; s += NTHR) {
    int m = s/(K2S*64), r = s - m*(K2S*64);
    int kt = r >> 6, l = r & 63;
    int cc = l & 15, qq = l >> 4;
    int d = m*16 + cc;
    short8 v;
    #pragma unroll
    for (int e = 0; e < 8; ++e) {
      int k = kt*32 + (e>>2)*16 + qq*4 + (e&3);
      float f = 0.f;
      if (d < DIN) {
        if (k < DHID)       f = W2p[d*DHID + k] * al1p[k];
        else if (k == DHID) f = B2C[d];
      }
      v[e] = (short)f2b(f);
    }
    *(short8*)&W2F[(size_t)s*8] = v;
  }
  __syncthreads();

  const float a1v = a1p[0];
  const float a2v = a2p[0];

  const u16* pW1 = W1F + (size_t)lane*8;   // fragment reads: base + imm offsets
  const u16* pW2 = W2F + (size_t)lane*8;
  float* XB = XYB + w*1248;                // this wave's x block [16][39] f32
  float* YB = XB + 624;                    // this wave's y block [16][39] f32
  const float* xrow = XB + c*39;           // token (wr+c) rows
  const float* yrow = YB + c*39;

  // 11 iterations: 10 full (192 tokens) + 1 partial (128 tokens, waves 0-7).
  // No in-loop barriers; all guards wave-uniform.
  #pragma unroll 1
  for (int it = 0; it <= FIT; ++it) {
    if (it == FIT && w >= 8) break;
    const int tb = blockTok + it * TPI;

    // ---- stage this iteration's x/y (f32) into LDS via global_load_lds ----
    // prior-iter LDS reads must drain before glds writes land (WAR)
    asm volatile("s_waitcnt lgkmcnt(0)" ::: "memory");
    __builtin_amdgcn_sched_barrier(0);
    {
      const float* xg = xp + (size_t)(tb + wr) * KPS;  // wave-uniform, 16B aligned
      const float* yg = yp + (size_t)(tb + wr) * KPS;
      glds16(xg + (size_t)lane*4,         XB);
      glds16(xg + (size_t)(64+lane)*4,    XB + 256);
      glds16(yg + (size_t)lane*4,         YB);
      glds16(yg + (size_t)(64+lane)*4,    YB + 256);
      if (lane < 28) {
        glds16(xg + (size_t)(128+lane)*4, XB + 512);
        glds16(yg + (size_t)(128+lane)*4, YB + 512);
      }
    }
    asm volatile("s_waitcnt vmcnt(0)" ::: "memory");
    __builtin_amdgcn_sched_barrier(0);

    // ---- GEMM1: h[j][t] = sum_k W1[j][k]*joined[t][k] + b1[j] (via frag slot) ----
    float4v acc1[M1T];
    #pragma unroll
    for (int m = 0; m < M1T; ++m)
      #pragma unroll
      for (int q = 0; q < 4; ++q) acc1[m][q] = 0.f;

    #pragma unroll
    for (int kt = 0; kt < K1S; ++kt) {
      // build B-fragment from f32 LDS per the W1F column permutation
      float bv[8];
      if (kt == 0) {
        const float* p = xrow + quad*8;
        #pragma unroll
        for (int e = 0; e < 8; ++e) bv[e] = p[e];
      } else if (kt == 1) {
        const float* p = (quad == 0) ? (xrow + 32) : (yrow + (quad-1)*8);
        #pragma unroll
        for (int e = 0; e < 8; ++e) bv[e] = p[e];
        if (quad == 0) bv[7] = 0.f;              // dead slot
      } else {
        if (quad < 2) {
          const float* p = (quad == 0) ? (yrow + 24) : (yrow + 32);
          #pragma unroll
          for (int e = 0; e < 8; ++e) bv[e] = p[e];
          if (quad == 1) bv[7] = 0.f;            // dead slot
        } else {
          #pragma unroll
          for (int e = 0; e < 8; ++e) bv[e] = 0.f;
          if (quad == 2) bv[0] = 1.f;            // b1 multiplier
        }
      }
      uint4v bu;
      #pragma unroll
      for (int j = 0; j < 4; ++j)
        bu[j] = (u32)f2b(bv[2*j]) | ((u32)f2b(bv[2*j+1]) << 16);
      short8 bfr = __builtin_bit_cast(short8, bu);
      #pragma unroll
      for (int m = 0; m < M1T; ++m) {
        short8 afr = *(const short8*)&pW1[(m*K1S + kt)*512];
        acc1[m] = __builtin_amdgcn_mfma_f32_16x16x32_bf16(afr, bfr, acc1[m], 0, 0, 0);
      }
    }

    // ---- PReLU + LN1 over 195 (pad rows are exact 0) ----
    float sum = 0.f, ss = 0.f;
    #pragma unroll
    for (int m = 0; m < M1T; ++m)
      #pragma unroll
      for (int q = 0; q < 4; ++q) {
        float h = acc1[m][q];
        float p = fmaxf(h, 0.f) + a1v * fminf(h, 0.f);
        acc1[m][q] = p;
        sum += p;
        ss = __builtin_fmaf(p, p, ss);
      }
    sum += __shfl_xor(sum, 16, 64);
    sum += __shfl_xor(sum, 32, 64);
    ss  += __shfl_xor(ss,  16, 64);
    ss  += __shfl_xor(ss,  32, 64);
    const float mean = sum * (1.f/DHID);
    const float istd = rsqrtf(ss*(1.f/DHID) - mean*mean + 1e-5f);

    // ---- pack normalized hidden into bf16 pairs IN REGISTERS ----
    u32 pn[26];
    #pragma unroll
    for (int m = 0; m < 12; ++m) {
      u16 p0 = f2b((acc1[m][0] - mean)*istd);
      u16 p1 = f2b((acc1[m][1] - mean)*istd);
      u16 p2 = f2b((acc1[m][2] - mean)*istd);
      u16 p3 = f2b((acc1[m][3] - mean)*istd);
      pn[2*m]   = (u32)p0 | ((u32)p1 << 16);
      pn[2*m+1] = (u32)p2 | ((u32)p3 << 16);
    }
    {
      // m=12: rows 192+quad*4+q. quad 0 -> {192,193,194, bias=1.0}; quads 1-3 -> 0
      float n0 = (quad == 0) ? (acc1[12][0] - mean)*istd : 0.f;
      float n1 = (quad == 0) ? (acc1[12][1] - mean)*istd : 0.f;
      float n2 = (quad == 0) ? (acc1[12][2] - mean)*istd : 0.f;
      u16 pb = (quad == 0) ? (u16)0x3F80 : (u16)0;
      pn[24] = (u32)f2b(n0) | ((u32)f2b(n1) << 16);
      pn[25] = (u32)f2b(n2) | ((u32)pb    << 16);
    }

    // ---- GEMM2: B-fragment is the lane's own pn[] thanks to the W2F K-perm ----
    float4v acc2[M2T];
    #pragma unroll
    for (int m = 0; m < M2T; ++m)
      #pragma unroll
      for (int q = 0; q < 4; ++q) acc2[m][q] = 0.f;

    #pragma unroll
    for (int kt = 0; kt < K2S; ++kt) {
      uint4v bu;
      bu[0] = pn[4*kt + 0];
      bu[1] = pn[4*kt + 1];
      bu[2] = (kt < 6) ? pn[4*kt + 2] : 0u;   // kt=6 upper half = rows 208..223 = pad
      bu[3] = (kt < 6) ? pn[4*kt + 3] : 0u;
      short8 bfr = __builtin_bit_cast(short8, bu);
      #pragma unroll
      for (int m = 0; m < M2T; ++m) {
        short8 afr = *(const short8*)&pW2[(m*K2S + kt)*512];
        acc2[m] = __builtin_amdgcn_mfma_f32_16x16x32_bf16(afr, bfr, acc2[m], 0, 0, 0);
      }
    }

    // ---- PReLU + LN2 + residual (f32 from LDS) + store ----
    float sum2 = 0.f, ss2 = 0.f;
    #pragma unroll
    for (int m = 0; m < M2T; ++m)
      #pragma unroll
      for (int q = 0; q < 4; ++q) {
        float h = acc2[m][q];
        float p = fmaxf(h, 0.f) + a2v * fminf(h, 0.f);
        acc2[m][q] = p;
        sum2 += p;
        ss2 = __builtin_fmaf(p, p, ss2);
      }
    sum2 += __shfl_xor(sum2, 16, 64);
    sum2 += __shfl_xor(sum2, 32, 64);
    ss2  += __shfl_xor(ss2,  16, 64);
    ss2  += __shfl_xor(ss2,  32, 64);
    const float mean2 = sum2 * (1.f/DIN);
    const float istd2 = rsqrtf(ss2*(1.f/DIN) - mean2*mean2 + 1e-5f);

    const int gt = tb + wr + c;
    #pragma unroll
    for (int m = 0; m < M2T; ++m) {
      int d0 = m*16 + quad*4;            // rows d0..d0+3, token c
      #pragma unroll
      for (int r = 0; r < 4; ++r) {
        int d = d0 + r;
        if (d < DIN) {
          float res = (d < KPS) ? xrow[d] : yrow[d - KPS];
          float2 ab = *(const float2*)&AB2[2*d];
          float  v  = (acc2[m][r] - mean2)*istd2*ab.x + ab.y + res;
          if (d < KPS) out0[(size_t)gt*KPS + d]         = v;
          else         out1[(size_t)gt*KPS + (d - KPS)] = v;
        }
      }
    }
  }
}

extern "C" void kernel_launch(void* const* d_in, const int* in_sizes, int n_in,
                              void* d_out, int out_size, void* d_ws, size_t ws_size,
                              hipStream_t stream) {
  const float* xp   = (const float*)d_in[0];
  const float* yp   = (const float*)d_in[1];
  const float* W1p  = (const float*)d_in[2];
  const float* b1p  = (const float*)d_in[3];
  const float* W2p  = (const float*)d_in[4];
  const float* b2p  = (const float*)d_in[5];
  const float* a1p  = (const float*)d_in[6];
  const float* a2p  = (const float*)d_in[7];
  const float* al1p = (const float*)d_in[8];
  const float* be1p = (const float*)d_in[9];
  const float* al2p = (const float*)d_in[10];
  const float* be2p = (const float*)d_in[11];

  float* out0 = (float*)d_out;
  float* out1 = out0 + (size_t)NTOKTOT * KPS;

  hipFuncSetAttribute((const void*)fused_mlp_kernel,
                      hipFuncAttributeMaxDynamicSharedMemorySize, SMEM_BYTES);

  fused_mlp_kernel<<<NBLK, NTHR, SMEM_BYTES, stream>>>(
      xp, yp, W1p, b1p, W2p, b2p, a1p, a2p, al1p, be1p, al2p, be2p, out0, out1);
}